// Round 1
// 224.711 us; speedup vs baseline: 1.1016x; 1.1016x over previous
//
#include <hip/hip_runtime.h>

#define SEQ   4096
#define HH    4
#define SCALE 0.125f
// exp2-folded constants: p = exp2(s*SC2 + a2), SC2 = SCALE*log2(e)
#define SC2   0.18033688011112042f
#define C16   -23.083120654223414f   /* -16*log2(e) */

typedef __bf16 bf16x8 __attribute__((ext_vector_type(8)));
typedef __bf16 bf16x4 __attribute__((ext_vector_type(4)));
typedef float  f32x4  __attribute__((ext_vector_type(4)));

// ---- ws layout (float offsets) ----
// Facts: inputs fp32, output fp32, ws >= 70.5 MB.
// Q frag-packed: [bh][tile16][frag2][512]; K frag-packed with PERMUTED rows:
//   [bh][jc32][tile2][frag2][512], tile row m <-> j = (m>>2)*8 + t*4 + (m&3)
//   so S^T = mfma(K,Q) yields lane(quad,mrow): j = quad*8 + t*4 + r, i = mrow
//   which is exactly the PV B-fragment layout (no cross-lane redistribution).
// V: [bh][jc32][nd4][512].
constexpr size_t OFF_W16  = 0;         // 4x65536 bf16 weights row-major
constexpr size_t OFF_A    = 131072;    // [bh*S+j] a2_j = (-16 - ln(Z_j))*log2e
constexpr size_t OFF_AO   = 294912;    // [8192][256] fp32 attn out (atomic)
constexpr size_t OFF_X16  = 9732096;   // 6291456 bf16 (x cast)
constexpr size_t OFF_Q16  = 12877824;  // packed Q,K,V bf16 regions
constexpr size_t K16OFF   = 2097152;
constexpr size_t V16OFF   = 4194304;
constexpr size_t OFF_PZ   = 16023552;  // [8][32768] colstats partials

__device__ __forceinline__ f32x4 mf(bf16x8 a, bf16x8 b, f32x4 c) {
    return __builtin_amdgcn_mfma_f32_16x16x32_bf16(a, b, c, 0, 0, 0);
}

// async global->LDS, 16B/lane; global ptr per-lane, LDS base wave-uniform
__device__ __forceinline__ void gload16(const __bf16* g, __bf16* l) {
    __builtin_amdgcn_global_load_lds(
        (const __attribute__((address_space(1))) unsigned int*)g,
        (__attribute__((address_space(3))) unsigned int*)l, 16, 0, 0);
}

__device__ __forceinline__ float ex2(float x) {
    return __builtin_amdgcn_exp2f(x);
}

// ---- prep: cast x, cast weights, zero AO — one kernel ----
__global__ void k_prep(const float* __restrict__ x,
                       const float* __restrict__ wq, const float* __restrict__ wk,
                       const float* __restrict__ wv, const float* __restrict__ wo,
                       float* __restrict__ ws) {
    int bx = blockIdx.x, t = threadIdx.x;
    if (bx < 6144) {
        size_t i4 = ((size_t)bx * 256 + t) * 4;
        float4 v = *(const float4*)(x + i4);
        bf16x4 o = {(__bf16)v.x, (__bf16)v.y, (__bf16)v.z, (__bf16)v.w};
        *(bf16x4*)((__bf16*)(ws + OFF_X16) + i4) = o;
    } else if (bx < 6400) {
        int q = bx - 6144;
        int y = q >> 6;
        const float* src = (y == 0) ? wq : (y == 1) ? wk : (y == 2) ? wv : wo;
        size_t i4 = ((size_t)(q & 63) * 256 + t) * 4;
        float4 v = *(const float4*)(src + i4);
        bf16x4 o = {(__bf16)v.x, (__bf16)v.y, (__bf16)v.z, (__bf16)v.w};
        *(bf16x4*)((__bf16*)(ws + OFF_W16) + (size_t)y * 65536 + i4) = o;
    } else {
        size_t i4 = ((size_t)(bx - 6400) * 256 + t) * 4;
        *(float4*)(ws + OFF_AO + i4) = make_float4(0.f, 0.f, 0.f, 0.f);
    }
}

// ---- QKV projection via MFMA; epilogue writes frag-packed layouts ----
__global__ __launch_bounds__(256) void k_qkv_mfma(const float* __restrict__ bq,
                                                  const float* __restrict__ bk,
                                                  const float* __restrict__ bv,
                                                  float* __restrict__ ws) {
    int t = threadIdx.x, lane = t & 63, w = t >> 6;
    int yw = blockIdx.y;
    int row0 = blockIdx.x * 64 + w * 16;
    int mrow = lane & 15, quad = lane >> 4;
    const __bf16* X16 = (const __bf16*)(ws + OFF_X16);
    const __bf16* W16 = (const __bf16*)(ws + OFF_W16) + (size_t)yw * 65536;
    const float* bias = (yw == 0) ? bq : (yw == 1) ? bk : bv;
    __bf16* Qb = (__bf16*)(ws + OFF_Q16);
    f32x4 acc[16];
#pragma unroll
    for (int n = 0; n < 16; n++) acc[n] = {0.f, 0.f, 0.f, 0.f};
    const __bf16* ap = X16 + (size_t)(row0 + mrow) * 768 + yw * 256 + quad * 8;
    const __bf16* bp = W16 + (size_t)mrow * 256 + quad * 8;
    for (int kc = 0; kc < 256; kc += 32) {
        bf16x8 a = *(const bf16x8*)(ap + kc);
#pragma unroll
        for (int nt = 0; nt < 16; nt++) {
            bf16x8 b = *(const bf16x8*)(bp + (size_t)nt * 16 * 256 + kc);
            acc[nt] = mf(a, b, acc[nt]);
        }
    }
#pragma unroll
    for (int nt = 0; nt < 16; nt++) {
        int n = nt * 16 + mrow;
        float bb = bias[n];
        int h = n >> 6, d = n & 63;
#pragma unroll
        for (int r = 0; r < 4; r++) {
            int sg = row0 + quad * 4 + r;
            int b_ = sg >> 12, s = sg & 4095;
            int bh = b_ * HH + h;
            float val = acc[nt][r] + bb;
            if (yw == 0) {
                int tile = s >> 4, m = s & 15, frag = d >> 5, q2 = (d >> 3) & 3, e = d & 7;
                size_t idx = (((size_t)bh * 256 + tile) * 2 + frag) * 512 +
                             (size_t)(q2 * 16 + m) * 8 + e;
                Qb[idx] = (__bf16)val;
            } else if (yw == 1) {
                // permuted K rows: row m holds j with (jj>>2)&1 = tile, see header
                int jc = s >> 5, jj = s & 31;
                int tl = (jj >> 2) & 1, m = ((jj >> 3) << 2) | (jj & 3);
                int frag = d >> 5, q2 = (d >> 3) & 3, e = d & 7;
                size_t idx = (((size_t)bh * 128 + jc) * 4 + tl * 2 + frag) * 512 +
                             (size_t)(q2 * 16 + m) * 8 + e;
                Qb[K16OFF + idx] = (__bf16)val;
            } else {
                int jc = s >> 5, qk = (s >> 3) & 3, e = s & 7;
                int nd = d >> 4, nl = d & 15;
                size_t idx = (((size_t)bh * 128 + jc) * 4 + nd) * 512 +
                             (size_t)(qk * 16 + nl) * 8 + e;
                Qb[V16OFF + idx] = (__bf16)val;
            }
        }
    }
}

// ---- pass 1: Z_j = sum_i exp(s_ij - 16); 32 j/wave, Q staged in LDS ----
// grid (32 jb, 8 iy, 8 bh) = 2048 blocks -> 8/CU; Q chunks of 64 i dbuf'd.
__global__ __launch_bounds__(256) void k_colstats(float* __restrict__ ws) {
    __shared__ __bf16 qbuf[2][4096];
    int t = threadIdx.x, lane = t & 63, w = t >> 6;
    int jb = blockIdx.x, iy = blockIdx.y, bh = blockIdx.z;
    int jc = jb * 4 + w;
    const __bf16* Qp = (const __bf16*)(ws + OFF_Q16);
    const __bf16* Kp = Qp + K16OFF;
    const __bf16* kb = Kp + ((size_t)(bh * 128 + jc) * 4) * 512 + lane * 8;
    bf16x8 bk00 = *(const bf16x8*)(kb);          // tileA frag0
    bf16x8 bk01 = *(const bf16x8*)(kb + 512);    // tileA frag1
    bf16x8 bk10 = *(const bf16x8*)(kb + 1024);   // tileB frag0
    bf16x8 bk11 = *(const bf16x8*)(kb + 1536);   // tileB frag1
    // stage chunk 0
    const __bf16* q0 = Qp + ((size_t)(bh * 256 + iy * 32) * 2) * 512 +
                       w * 1024 + lane * 8;
    gload16(q0, qbuf[0] + w * 1024);
    gload16(q0 + 512, qbuf[0] + w * 1024 + 512);
    __syncthreads();
    float z0 = 0.f, z1 = 0.f;
    for (int ic = 0; ic < 8; ic++) {
        const __bf16* cur = qbuf[ic & 1];
        if (ic < 7) {
            const __bf16* qn = Qp + ((size_t)(bh * 256 + iy * 32 + (ic + 1) * 4) * 2) * 512 +
                               w * 1024 + lane * 8;
            gload16(qn, qbuf[(ic + 1) & 1] + w * 1024);
            gload16(qn + 512, qbuf[(ic + 1) & 1] + w * 1024 + 512);
        }
#pragma unroll
        for (int it = 0; it < 4; it++) {
            bf16x8 a0 = *(const bf16x8*)(cur + it * 1024 + lane * 8);
            bf16x8 a1 = *(const bf16x8*)(cur + it * 1024 + 512 + lane * 8);
            f32x4 c0 = {0.f, 0.f, 0.f, 0.f};
            c0 = mf(a0, bk00, c0);
            c0 = mf(a1, bk01, c0);
            f32x4 c1 = {0.f, 0.f, 0.f, 0.f};
            c1 = mf(a0, bk10, c1);
            c1 = mf(a1, bk11, c1);
#pragma unroll
            for (int r = 0; r < 4; r++) {
                z0 += ex2(fmaf(c0[r], SC2, C16));
                z1 += ex2(fmaf(c1[r], SC2, C16));
            }
        }
        __syncthreads();
    }
    z0 += __shfl_xor(z0, 16, 64);
    z0 += __shfl_xor(z0, 32, 64);
    z1 += __shfl_xor(z1, 16, 64);
    z1 += __shfl_xor(z1, 32, 64);
    if (lane < 16) {
        // col m of tileA/tileB -> j = jc*32 + (m>>2)*8 + {0,4} + (m&3)
        size_t o = OFF_PZ + (size_t)iy * 32768 + (size_t)bh * SEQ +
                   jc * 32 + ((lane >> 2) << 3) + (lane & 3);
        ws[o] = z0;
        ws[o + 4] = z1;
    }
}

// ---- pass 1b: a2_j = (-16 - ln(sum of partials)) * log2e ----
__global__ void k_afin(float* __restrict__ ws) {
    int idx = blockIdx.x * 256 + threadIdx.x;
    const float* pz = ws + OFF_PZ;
    float Z = 0.f;
#pragma unroll
    for (int y = 0; y < 8; y++) Z += pz[(size_t)y * 32768 + idx];
    ws[OFF_A + idx] = C16 - __log2f(Z);
}

// ---- pass 2: transposed S^T/PV^T, all-register P, 16 i/wave ----
// grid (64 ib, 4 jy, 8 bh) = 2048 blocks -> 8/CU; K/V dbuf, a2 in LDS.
// S^T = mfma(K,Q): lane holds p[j=quad*8+t*4+r][i=mrow] -> directly the PV
// B-fragment. PV^T = mfma(V,P): oaccT lane holds out[d=nd*16+quad*4+r][i=mrow].
// Epilogue: wave-local LDS transpose (reusing K/V space) -> coalesced atomics.
__global__ __launch_bounds__(256) void k_attnpv(float* __restrict__ ws) {
    __shared__ __align__(16) char pool[20480];
    __bf16* ldsK = (__bf16*)pool;            // [2][2048]
    __bf16* ldsV = (__bf16*)(pool + 8192);   // [2][2048]
    float*  sA   = (float*)(pool + 16384);   // [1024]
    int t = threadIdx.x, lane = t & 63, w = t >> 6;
    int jy = blockIdx.y, bh = blockIdx.z;
    int it0 = blockIdx.x * 4 + w;
    int i0 = it0 * 16;
    int mrow = lane & 15, quad = lane >> 4;
    const __bf16* Qp = (const __bf16*)(ws + OFF_Q16);
    const __bf16* Kp = Qp + K16OFF;
    const __bf16* Vp = Qp + V16OFF;
    int jbase = jy * 1024;
    // stage a2 coefficients for this j-range (1024 floats)
    {
        const float* Ag = ws + OFF_A + (size_t)bh * SEQ + jbase;
        *(float4*)(sA + t * 4) = *(const float4*)(Ag + t * 4);
    }
    const __bf16* qb = Qp + ((size_t)(bh * 256 + it0) * 2) * 512 + lane * 8;
    bf16x8 aq0 = *(const bf16x8*)(qb);
    bf16x8 aq1 = *(const bf16x8*)(qb + 512);
    f32x4 oaccT[4];
#pragma unroll
    for (int nd = 0; nd < 4; nd++) oaccT[nd] = {0.f, 0.f, 0.f, 0.f};
    int c0g = jy * 32;  // first 32-j chunk
    {
        const __bf16* kg = Kp + ((size_t)(bh * 128 + c0g) * 4) * 512 + w * 512 + lane * 8;
        gload16(kg, ldsK + w * 512);
        const __bf16* vg = Vp + ((size_t)(bh * 128 + c0g) * 4) * 512 + w * 512 + lane * 8;
        gload16(vg, ldsV + w * 512);
    }
    __syncthreads();

    for (int jt = 0; jt < 32; jt++) {
        const __bf16* curK = ldsK + (jt & 1) * 2048;
        const __bf16* curV = ldsV + (jt & 1) * 2048;
        if (jt < 31) {
            int cn = c0g + jt + 1;
            const __bf16* kg = Kp + ((size_t)(bh * 128 + cn) * 4) * 512 + w * 512 + lane * 8;
            gload16(kg, ldsK + ((jt + 1) & 1) * 2048 + w * 512);
            const __bf16* vg = Vp + ((size_t)(bh * 128 + cn) * 4) * 512 + w * 512 + lane * 8;
            gload16(vg, ldsV + ((jt + 1) & 1) * 2048 + w * 512);
        }
        f32x4 a4L = *(const f32x4*)(sA + jt * 32 + quad * 8);
        f32x4 a4H = *(const f32x4*)(sA + jt * 32 + quad * 8 + 4);
        bf16x8 ck0 = *(const bf16x8*)(curK + lane * 8);
        bf16x8 ck1 = *(const bf16x8*)(curK + 512 + lane * 8);
        bf16x8 ck2 = *(const bf16x8*)(curK + 1024 + lane * 8);
        bf16x8 ck3 = *(const bf16x8*)(curK + 1536 + lane * 8);
        f32x4 cT0 = {0.f, 0.f, 0.f, 0.f};
        cT0 = mf(ck0, aq0, cT0);
        cT0 = mf(ck1, aq1, cT0);
        f32x4 cT1 = {0.f, 0.f, 0.f, 0.f};
        cT1 = mf(ck2, aq0, cT1);
        cT1 = mf(ck3, aq1, cT1);
        bf16x8 pb;
#pragma unroll
        for (int r = 0; r < 4; r++) {
            pb[r]     = (__bf16)ex2(fmaf(cT0[r], SC2, a4L[r]));  // j=quad*8+r
            pb[4 + r] = (__bf16)ex2(fmaf(cT1[r], SC2, a4H[r]));  // j=quad*8+4+r
        }
#pragma unroll
        for (int nd = 0; nd < 4; nd++) {
            bf16x8 bv = *(const bf16x8*)(curV + nd * 512 + lane * 8);
            oaccT[nd] = mf(bv, pb, oaccT[nd]);  // out^T accumulate
        }
        __syncthreads();
    }

    // epilogue: wave-local transpose through LDS (K/V buffers are dead),
    // then fully-coalesced fp32 atomics (64 consecutive floats per instr).
    float* sO = (float*)pool + (size_t)w * (16 * 65);
#pragma unroll
    for (int nd = 0; nd < 4; nd++)
#pragma unroll
        for (int r = 0; r < 4; r++)
            sO[mrow * 65 + nd * 16 + quad * 4 + r] = oaccT[nd][r];
    int b = bh >> 2, h = bh & 3;
    float* AO = ws + OFF_AO;
#pragma unroll
    for (int c = 0; c < 16; c++) {
        atomicAdd(&AO[((size_t)(b * SEQ + i0 + c)) * 256 + h * 64 + lane],
                  sO[c * 65 + lane]);
    }
}

// ---- output projection: fp32 AO -> bf16 frags inline, MFMA, fp32 out ----
__global__ __launch_bounds__(256) void k_outproj_mfma(const float* __restrict__ bo,
                                                      float* __restrict__ ws,
                                                      float* __restrict__ out) {
    int t = threadIdx.x, lane = t & 63, w = t >> 6;
    int row0 = blockIdx.x * 64 + w * 16;
    int mrow = lane & 15, quad = lane >> 4;
    const float* AO = ws + OFF_AO;
    const __bf16* W16 = (const __bf16*)(ws + OFF_W16) + (size_t)3 * 65536;
    f32x4 acc[16];
#pragma unroll
    for (int n = 0; n < 16; n++) acc[n] = {0.f, 0.f, 0.f, 0.f};
    const float* ap = AO + (size_t)(row0 + mrow) * 256 + quad * 8;
    const __bf16* bp = W16 + (size_t)mrow * 256 + quad * 8;
    for (int kc = 0; kc < 256; kc += 32) {
        float4 u = *(const float4*)(ap + kc);
        float4 v = *(const float4*)(ap + kc + 4);
        bf16x8 a = {(__bf16)u.x, (__bf16)u.y, (__bf16)u.z, (__bf16)u.w,
                    (__bf16)v.x, (__bf16)v.y, (__bf16)v.z, (__bf16)v.w};
#pragma unroll
        for (int nt = 0; nt < 16; nt++) {
            bf16x8 b = *(const bf16x8*)(bp + (size_t)nt * 16 * 256 + kc);
            acc[nt] = mf(a, b, acc[nt]);
        }
    }
#pragma unroll
    for (int nt = 0; nt < 16; nt++) {
        int n = nt * 16 + mrow;
        float bb = bo[n];
#pragma unroll
        for (int r = 0; r < 4; r++) {
            int sg = row0 + quad * 4 + r;
            out[(size_t)sg * 256 + n] = acc[nt][r] + bb;
        }
    }
}

extern "C" void kernel_launch(void* const* d_in, const int* in_sizes, int n_in,
                              void* d_out, int out_size, void* d_ws, size_t ws_size,
                              hipStream_t stream) {
    const float* x  = (const float*)d_in[0];
    const float* wq = (const float*)d_in[1];
    const float* bq = (const float*)d_in[2];
    const float* wk = (const float*)d_in[3];
    const float* bk = (const float*)d_in[4];
    const float* wv = (const float*)d_in[5];
    const float* bv = (const float*)d_in[6];
    const float* wo = (const float*)d_in[7];
    const float* bo = (const float*)d_in[8];
    float* ws = (float*)d_ws;
    float* out = (float*)d_out;

    k_prep<<<8448, 256, 0, stream>>>(x, wq, wk, wv, wo, ws);
    k_qkv_mfma<<<dim3(128, 3), 256, 0, stream>>>(bq, bk, bv, ws);
    k_colstats<<<dim3(32, 8, 8), 256, 0, stream>>>(ws);
    k_afin<<<128, 256, 0, stream>>>(ws);
    k_attnpv<<<dim3(64, 4, 8), 256, 0, stream>>>(ws);
    k_outproj_mfma<<<128, 256, 0, stream>>>(bo, ws, out);
}

// Round 4
// 213.548 us; speedup vs baseline: 1.1592x; 1.0523x over previous
//
#include <hip/hip_runtime.h>

#define SEQ   4096
#define HH    4
#define SCALE 0.125f
// exp2-folded constants: p = exp2(s*SC2 + a2), SC2 = SCALE*log2(e).
// SC2 is folded into Q at projection time (wq,bq pre-scaled), so the exp
// argument is just (accumulator + bias), and the bias rides in the MFMA C-init.
#define SC2   0.18033688011112042f
#define C16   -23.083120654223414f   /* -16*log2(e) */

typedef __bf16 bf16x8 __attribute__((ext_vector_type(8)));
typedef __bf16 bf16x4 __attribute__((ext_vector_type(4)));
typedef float  f32x4  __attribute__((ext_vector_type(4)));

// ---- ws layout (float offsets) ----
// Q frag-packed: [bh][tile16][frag2][512] (Q pre-scaled by SC2);
// K frag-packed with PERMUTED rows: [bh][jc32][tile2][frag2][512],
//   tile row m <-> j = (m>>2)*8 + t*4 + (m&3) so S^T = mfma(K,Q) lands
//   directly in the PV B-fragment layout (no cross-lane redistribution).
// V: [bh][jc32][nd4][512].
constexpr size_t OFF_W16  = 0;         // 4x65536 bf16 weights (wq slab pre-scaled by SC2)
constexpr size_t OFF_A    = 131072;    // [bh*S+j] a2_j = C16 - log2(Z_j)
constexpr size_t OFF_AO   = 294912;    // [8192][256] fp32 attn out (atomic)
constexpr size_t OFF_X16  = 9732096;   // 6291456 bf16 (x cast)
constexpr size_t OFF_Q16  = 12877824;  // packed Q,K,V bf16 regions
constexpr size_t K16OFF   = 2097152;
constexpr size_t V16OFF   = 4194304;
constexpr size_t OFF_PZ   = 16023552;  // [8][32768] colstats partials

__device__ __forceinline__ f32x4 mf(bf16x8 a, bf16x8 b, f32x4 c) {
    return __builtin_amdgcn_mfma_f32_16x16x32_bf16(a, b, c, 0, 0, 0);
}

__device__ __forceinline__ void gload16(const __bf16* g, __bf16* l) {
    __builtin_amdgcn_global_load_lds(
        (const __attribute__((address_space(1))) unsigned int*)g,
        (__attribute__((address_space(3))) unsigned int*)l, 16, 0, 0);
}

__device__ __forceinline__ float ex2(float x) {
    return __builtin_amdgcn_exp2f(x);
}

// ---- prep: cast x, cast weights (wq pre-scaled by SC2), zero AO ----
__global__ void k_prep(const float* __restrict__ x,
                       const float* __restrict__ wq, const float* __restrict__ wk,
                       const float* __restrict__ wv, const float* __restrict__ wo,
                       float* __restrict__ ws) {
    int bx = blockIdx.x, t = threadIdx.x;
    if (bx < 6144) {
        size_t i4 = ((size_t)bx * 256 + t) * 4;
        float4 v = *(const float4*)(x + i4);
        bf16x4 o = {(__bf16)v.x, (__bf16)v.y, (__bf16)v.z, (__bf16)v.w};
        *(bf16x4*)((__bf16*)(ws + OFF_X16) + i4) = o;
    } else if (bx < 6400) {
        int q = bx - 6144;
        int y = q >> 6;
        const float* src = (y == 0) ? wq : (y == 1) ? wk : (y == 2) ? wv : wo;
        float sc = (y == 0) ? SC2 : 1.0f;
        size_t i4 = ((size_t)(q & 63) * 256 + t) * 4;
        float4 v = *(const float4*)(src + i4);
        bf16x4 o = {(__bf16)(v.x * sc), (__bf16)(v.y * sc),
                    (__bf16)(v.z * sc), (__bf16)(v.w * sc)};
        *(bf16x4*)((__bf16*)(ws + OFF_W16) + (size_t)y * 65536 + i4) = o;
    } else {
        size_t i4 = ((size_t)(bx - 6400) * 256 + t) * 4;
        *(float4*)(ws + OFF_AO + i4) = make_float4(0.f, 0.f, 0.f, 0.f);
    }
}

// ---- QKV projection; grid (128, 3, 2): z splits the 256-col output ----
__global__ __launch_bounds__(256) void k_qkv_mfma(const float* __restrict__ bq,
                                                  const float* __restrict__ bk,
                                                  const float* __restrict__ bv,
                                                  float* __restrict__ ws) {
    int t = threadIdx.x, lane = t & 63, w = t >> 6;
    int yw = blockIdx.y;
    int ntb = blockIdx.z * 8;
    int row0 = blockIdx.x * 64 + w * 16;
    int mrow = lane & 15, quad = lane >> 4;
    const __bf16* X16 = (const __bf16*)(ws + OFF_X16);
    const __bf16* W16 = (const __bf16*)(ws + OFF_W16) + (size_t)yw * 65536;
    const float* bias = (yw == 0) ? bq : (yw == 1) ? bk : bv;
    __bf16* Qb = (__bf16*)(ws + OFF_Q16);
    f32x4 acc[8];
#pragma unroll
    for (int n = 0; n < 8; n++) acc[n] = {0.f, 0.f, 0.f, 0.f};
    const __bf16* ap = X16 + (size_t)(row0 + mrow) * 768 + yw * 256 + quad * 8;
    const __bf16* bp = W16 + (size_t)ntb * 4096 + (size_t)mrow * 256 + quad * 8;
    for (int kc = 0; kc < 256; kc += 32) {
        bf16x8 a = *(const bf16x8*)(ap + kc);
#pragma unroll
        for (int nt = 0; nt < 8; nt++) {
            bf16x8 b = *(const bf16x8*)(bp + (size_t)nt * 4096 + kc);
            acc[nt] = mf(a, b, acc[nt]);
        }
    }
#pragma unroll
    for (int nt = 0; nt < 8; nt++) {
        int n = (ntb + nt) * 16 + mrow;
        float bb = bias[n];
        if (yw == 0) bb *= SC2;
        int h = n >> 6, d = n & 63;
#pragma unroll
        for (int r = 0; r < 4; r++) {
            int sg = row0 + quad * 4 + r;
            int b_ = sg >> 12, s = sg & 4095;
            int bh = b_ * HH + h;
            float val = acc[nt][r] + bb;
            if (yw == 0) {
                int tile = s >> 4, m = s & 15, frag = d >> 5, q2 = (d >> 3) & 3, e = d & 7;
                size_t idx = (((size_t)bh * 256 + tile) * 2 + frag) * 512 +
                             (size_t)(q2 * 16 + m) * 8 + e;
                Qb[idx] = (__bf16)val;
            } else if (yw == 1) {
                int jc = s >> 5, jj = s & 31;
                int tl = (jj >> 2) & 1, m = ((jj >> 3) << 2) | (jj & 3);
                int frag = d >> 5, q2 = (d >> 3) & 3, e = d & 7;
                size_t idx = (((size_t)bh * 128 + jc) * 4 + tl * 2 + frag) * 512 +
                             (size_t)(q2 * 16 + m) * 8 + e;
                Qb[K16OFF + idx] = (__bf16)val;
            } else {
                int jc = s >> 5, qk = (s >> 3) & 3, e = s & 7;
                int nd = d >> 4, nl = d & 15;
                size_t idx = (((size_t)bh * 128 + jc) * 4 + nd) * 512 +
                             (size_t)(qk * 16 + nl) * 8 + e;
                Qb[V16OFF + idx] = (__bf16)val;
            }
        }
    }
}

// ---- pass 1: Z_j partials; C16 folded into MFMA C-init (no fmaf) ----
__global__ __launch_bounds__(256) void k_colstats(float* __restrict__ ws) {
    __shared__ __bf16 qbuf[2][4096];
    int t = threadIdx.x, lane = t & 63, w = t >> 6;
    int jb = blockIdx.x, iy = blockIdx.y, bh = blockIdx.z;
    int jc = jb * 4 + w;
    const __bf16* Qp = (const __bf16*)(ws + OFF_Q16);
    const __bf16* Kp = Qp + K16OFF;
    const __bf16* kb = Kp + ((size_t)(bh * 128 + jc) * 4) * 512 + lane * 8;
    bf16x8 bk00 = *(const bf16x8*)(kb);
    bf16x8 bk01 = *(const bf16x8*)(kb + 512);
    bf16x8 bk10 = *(const bf16x8*)(kb + 1024);
    bf16x8 bk11 = *(const bf16x8*)(kb + 1536);
    const __bf16* q0 = Qp + ((size_t)(bh * 256 + iy * 32) * 2) * 512 +
                       w * 1024 + lane * 8;
    gload16(q0, qbuf[0] + w * 1024);
    gload16(q0 + 512, qbuf[0] + w * 1024 + 512);
    __syncthreads();
    const f32x4 cin = {C16, C16, C16, C16};
    float z0 = 0.f, z1 = 0.f;
    for (int ic = 0; ic < 8; ic++) {
        const __bf16* cur = qbuf[ic & 1];
        if (ic < 7) {
            const __bf16* qn = Qp + ((size_t)(bh * 256 + iy * 32 + (ic + 1) * 4) * 2) * 512 +
                               w * 1024 + lane * 8;
            gload16(qn, qbuf[(ic + 1) & 1] + w * 1024);
            gload16(qn + 512, qbuf[(ic + 1) & 1] + w * 1024 + 512);
        }
#pragma unroll
        for (int it = 0; it < 4; it++) {
            bf16x8 a0 = *(const bf16x8*)(cur + it * 1024 + lane * 8);
            bf16x8 a1 = *(const bf16x8*)(cur + it * 1024 + 512 + lane * 8);
            f32x4 c0 = mf(a0, bk00, cin);
            c0 = mf(a1, bk01, c0);
            f32x4 c1 = mf(a0, bk10, cin);
            c1 = mf(a1, bk11, c1);
#pragma unroll
            for (int r = 0; r < 4; r++) {
                z0 += ex2(c0[r]);
                z1 += ex2(c1[r]);
            }
        }
        __syncthreads();
    }
    z0 += __shfl_xor(z0, 16, 64);
    z0 += __shfl_xor(z0, 32, 64);
    z1 += __shfl_xor(z1, 16, 64);
    z1 += __shfl_xor(z1, 32, 64);
    if (lane < 16) {
        size_t o = OFF_PZ + (size_t)iy * 32768 + (size_t)bh * SEQ +
                   jc * 32 + ((lane >> 2) << 3) + (lane & 3);
        ws[o] = z0;
        ws[o + 4] = z1;
    }
}

// ---- pass 1b: a2_j = C16 - log2(sum of partials) ----
__global__ void k_afin(float* __restrict__ ws) {
    int idx = blockIdx.x * 256 + threadIdx.x;
    const float* pz = ws + OFF_PZ;
    float Z = 0.f;
#pragma unroll
    for (int y = 0; y < 8; y++) Z += pz[(size_t)y * 32768 + idx];
    ws[OFF_A + idx] = C16 - __log2f(Z);
}

// ---- pass 2: 32 i/wave (2 Q tiles share all K/V/a reads), a2 in MFMA C-init,
// a2 prefetched from global 1 iter ahead. grid (32,4,8)=1024 blocks. ----
__global__ __launch_bounds__(256) void k_attnpv(float* __restrict__ ws) {
    __shared__ __align__(16) char pool[17408];
    __bf16* ldsK = (__bf16*)pool;            // [2][2048]
    __bf16* ldsV = (__bf16*)(pool + 8192);   // [2][2048]
    int t = threadIdx.x, lane = t & 63, w = t >> 6;
    int jy = blockIdx.y, bh = blockIdx.z;
    int itp = blockIdx.x * 4 + w;      // 0..127
    int it0 = itp * 2;                 // two 16-row Q tiles: it0, it0+1
    int mrow = lane & 15, quad = lane >> 4;
    const __bf16* Qp = (const __bf16*)(ws + OFF_Q16);
    const __bf16* Kp = Qp + K16OFF;
    const __bf16* Vp = Qp + V16OFF;
    const float* Ag = ws + OFF_A + (size_t)bh * SEQ + jy * 1024 + quad * 8;

    const __bf16* qb = Qp + ((size_t)(bh * 256 + it0) * 2) * 512 + lane * 8;
    bf16x8 aq00 = *(const bf16x8*)(qb);
    bf16x8 aq01 = *(const bf16x8*)(qb + 512);
    bf16x8 aq10 = *(const bf16x8*)(qb + 1024);
    bf16x8 aq11 = *(const bf16x8*)(qb + 1536);

    f32x4 oT0[4], oT1[4];
#pragma unroll
    for (int nd = 0; nd < 4; nd++) {
        oT0[nd] = {0.f, 0.f, 0.f, 0.f};
        oT1[nd] = {0.f, 0.f, 0.f, 0.f};
    }
    int c0g = jy * 32;
    const __bf16* kg = Kp + ((size_t)(bh * 128 + c0g) * 4) * 512 + w * 512 + lane * 8;
    const __bf16* vg = Vp + ((size_t)(bh * 128 + c0g) * 4) * 512 + w * 512 + lane * 8;
    gload16(kg, ldsK + w * 512);
    gload16(vg, ldsV + w * 512);
    kg += 2048; vg += 2048;
    f32x4 aL = *(const f32x4*)(Ag);
    f32x4 aH = *(const f32x4*)(Ag + 4);
    __syncthreads();

    for (int jt = 0; jt < 32; jt++) {
        const __bf16* curK = ldsK + (jt & 1) * 2048;
        const __bf16* curV = ldsV + (jt & 1) * 2048;
        f32x4 aLn = aL, aHn = aH;
        if (jt < 31) {
            gload16(kg, ldsK + ((jt + 1) & 1) * 2048 + w * 512);
            gload16(vg, ldsV + ((jt + 1) & 1) * 2048 + w * 512);
            kg += 2048; vg += 2048;
            aLn = *(const f32x4*)(Ag + (jt + 1) * 32);
            aHn = *(const f32x4*)(Ag + (jt + 1) * 32 + 4);
        }
        bf16x8 ck0 = *(const bf16x8*)(curK + lane * 8);
        bf16x8 ck1 = *(const bf16x8*)(curK + 512 + lane * 8);
        bf16x8 ck2 = *(const bf16x8*)(curK + 1024 + lane * 8);
        bf16x8 ck3 = *(const bf16x8*)(curK + 1536 + lane * 8);
        // S^T with bias folded into C-init: c = s*SC2 + a2  (Q pre-scaled)
        f32x4 c00 = mf(ck0, aq00, aL); c00 = mf(ck1, aq01, c00);
        f32x4 c01 = mf(ck2, aq00, aH); c01 = mf(ck3, aq01, c01);
        f32x4 c10 = mf(ck0, aq10, aL); c10 = mf(ck1, aq11, c10);
        f32x4 c11 = mf(ck2, aq10, aH); c11 = mf(ck3, aq11, c11);
        bf16x8 pb0, pb1;
#pragma unroll
        for (int r = 0; r < 4; r++) {
            pb0[r]     = (__bf16)ex2(c00[r]);
            pb0[4 + r] = (__bf16)ex2(c01[r]);
            pb1[r]     = (__bf16)ex2(c10[r]);
            pb1[4 + r] = (__bf16)ex2(c11[r]);
        }
#pragma unroll
        for (int nd = 0; nd < 4; nd++) {
            bf16x8 bv = *(const bf16x8*)(curV + nd * 512 + lane * 8);
            oT0[nd] = mf(bv, pb0, oT0[nd]);
            oT1[nd] = mf(bv, pb1, oT1[nd]);
        }
        aL = aLn; aH = aHn;
        __syncthreads();
    }

    // epilogue: wave-local LDS transpose (pool is dead), coalesced atomics
    float* sO = (float*)pool + (size_t)w * 1040;   // 16 x 65 floats per wave
    int b = bh >> 2, h = bh & 3;
    float* AO = ws + OFF_AO;
    int i0 = it0 * 16;
#pragma unroll
    for (int nd = 0; nd < 4; nd++)
#pragma unroll
        for (int r = 0; r < 4; r++)
            sO[mrow * 65 + nd * 16 + quad * 4 + r] = oT0[nd][r];
#pragma unroll
    for (int c = 0; c < 16; c++)
        atomicAdd(&AO[((size_t)(b * SEQ + i0 + c)) * 256 + h * 64 + lane],
                  sO[c * 65 + lane]);
#pragma unroll
    for (int nd = 0; nd < 4; nd++)
#pragma unroll
        for (int r = 0; r < 4; r++)
            sO[mrow * 65 + nd * 16 + quad * 4 + r] = oT1[nd][r];
#pragma unroll
    for (int c = 0; c < 16; c++)
        atomicAdd(&AO[((size_t)(b * SEQ + i0 + 16 + c)) * 256 + h * 64 + lane],
                  sO[c * 65 + lane]);
}

// ---- output projection; grid (128, 4): y splits cols -> 512 blocks ----
__global__ __launch_bounds__(256) void k_outproj_mfma(const float* __restrict__ bo,
                                                      float* __restrict__ ws,
                                                      float* __restrict__ out) {
    int t = threadIdx.x, lane = t & 63, w = t >> 6;
    int row0 = blockIdx.x * 64 + w * 16;
    int ntb = blockIdx.y * 4;          // FIX: was blockIdx.z (grid has y=4, z=1)
    int mrow = lane & 15, quad = lane >> 4;
    const float* AO = ws + OFF_AO;
    const __bf16* W16 = (const __bf16*)(ws + OFF_W16) + (size_t)3 * 65536;
    f32x4 acc[4];
#pragma unroll
    for (int n = 0; n < 4; n++) acc[n] = {0.f, 0.f, 0.f, 0.f};
    const float* ap = AO + (size_t)(row0 + mrow) * 256 + quad * 8;
    const __bf16* bp = W16 + (size_t)ntb * 4096 + (size_t)mrow * 256 + quad * 8;
    for (int kc = 0; kc < 256; kc += 32) {
        float4 u = *(const float4*)(ap + kc);
        float4 v = *(const float4*)(ap + kc + 4);
        bf16x8 a = {(__bf16)u.x, (__bf16)u.y, (__bf16)u.z, (__bf16)u.w,
                    (__bf16)v.x, (__bf16)v.y, (__bf16)v.z, (__bf16)v.w};
#pragma unroll
        for (int nt = 0; nt < 4; nt++) {
            bf16x8 b = *(const bf16x8*)(bp + (size_t)nt * 4096 + kc);
            acc[nt] = mf(a, b, acc[nt]);
        }
    }
#pragma unroll
    for (int nt = 0; nt < 4; nt++) {
        int n = (ntb + nt) * 16 + mrow;
        float bb = bo[n];
#pragma unroll
        for (int r = 0; r < 4; r++) {
            int sg = row0 + quad * 4 + r;
            out[(size_t)sg * 256 + n] = acc[nt][r] + bb;
        }
    }
}

extern "C" void kernel_launch(void* const* d_in, const int* in_sizes, int n_in,
                              void* d_out, int out_size, void* d_ws, size_t ws_size,
                              hipStream_t stream) {
    const float* x  = (const float*)d_in[0];
    const float* wq = (const float*)d_in[1];
    const float* bq = (const float*)d_in[2];
    const float* wk = (const float*)d_in[3];
    const float* bk = (const float*)d_in[4];
    const float* wv = (const float*)d_in[5];
    const float* bv = (const float*)d_in[6];
    const float* wo = (const float*)d_in[7];
    const float* bo = (const float*)d_in[8];
    float* ws = (float*)d_ws;
    float* out = (float*)d_out;

    k_prep<<<8448, 256, 0, stream>>>(x, wq, wk, wv, wo, ws);
    k_qkv_mfma<<<dim3(128, 3, 2), 256, 0, stream>>>(bq, bk, bv, ws);
    k_colstats<<<dim3(32, 8, 8), 256, 0, stream>>>(ws);
    k_afin<<<128, 256, 0, stream>>>(ws);
    k_attnpv<<<dim3(32, 4, 8), 256, 0, stream>>>(ws);
    k_outproj_mfma<<<dim3(128, 4), 256, 0, stream>>>(bo, ws, out);
}